// Round 13
// baseline (631.556 us; speedup 1.0000x reference)
//
#include <hip/hip_runtime.h>
#include <hip/hip_bf16.h>

// Problem constants
#define N_AG   32
#define B_SZ   16384
#define SD_    128
#define AD_    64
#define IDIM_  192
#define H_     256
#define HEADS_ 4
#define AT_    64
#define NO_    31   // N_AG-1 "others"

typedef __attribute__((ext_vector_type(8))) short bf16x8_t;
typedef __attribute__((ext_vector_type(4))) float f32x4_t;
typedef __attribute__((ext_vector_type(4))) unsigned int u32x4_t;

__device__ inline unsigned short f2bfu(float f){
  union { __hip_bfloat16 h; unsigned short u; } cv;
  cv.h = __float2bfloat16(f);
  return cv.u;
}
__device__ inline float bflo(unsigned int u){
  union { float f; unsigned int i; } c; c.i = u << 16; return c.f;
}
__device__ inline float bfhi(unsigned int u){
  union { float f; unsigned int i; } c; c.i = u & 0xffff0000u; return c.f;
}

// async global->LDS 16B (dest = wave-uniform base + lane*16)
__device__ inline void gll16(const unsigned short* g, unsigned short* l) {
  __builtin_amdgcn_global_load_lds(
      (const __attribute__((address_space(1))) unsigned int*)g,
      (__attribute__((address_space(3))) unsigned int*)l, 16, 0, 0);
}

// 8-wide bf16 dot with f32 accumulate
__device__ inline float dot8(bf16x8_t a, bf16x8_t b, float acc){
  u32x4_t au = __builtin_bit_cast(u32x4_t, a);
  u32x4_t bu = __builtin_bit_cast(u32x4_t, b);
  #pragma unroll
  for (int i = 0; i < 4; i++) {
    acc = fmaf(bflo(au[i]), bflo(bu[i]), acc);
    acc = fmaf(bfhi(au[i]), bfhi(bu[i]), acc);
  }
  return acc;
}

// ==================== consolidated prep (transposes + Mct) ====================
__global__ __launch_bounds__(256) void k_prep(
    const float* __restrict__ encW, const float* __restrict__ sW,
    const float* __restrict__ mfW,  const float* __restrict__ mf2W,
    const float* __restrict__ W1,   const float* __restrict__ W2,
    const float* __restrict__ Wv,   const float* __restrict__ Wsel,
    const float* __restrict__ Wk,
    unsigned short* __restrict__ encWt, unsigned short* __restrict__ sWt,
    unsigned short* __restrict__ mfWt,  unsigned short* __restrict__ mf2Wt,
    unsigned short* __restrict__ W1t,   unsigned short* __restrict__ W2t,
    unsigned short* __restrict__ WvT,   unsigned short* __restrict__ Mct)
{
  const int bid = blockIdx.x, tid = threadIdx.x;
  auto tr = [&](const float* src, unsigned short* dst, int K, int N, int idx){
    int kn = K * N;
    int b = idx / kn, i = idx - b * kn;
    int n = i / K, k = i - n * K;
    dst[(long)b * kn + i] = f2bfu(src[(long)b * kn + (long)k * N + n]);
  };
  if (bid < 5952)        tr(encW + 192*256, encWt, 192, 256, bid*256 + tid);
  else if (bid < 6080)   tr(sW,   sWt,  128, 256, (bid-5952)*256 + tid);
  else if (bid < 6144)   tr(mfW,  mfWt,  64, 256, (bid-6080)*256 + tid);
  else if (bid < 6208)   tr(mf2W, mf2Wt, 64, 256, (bid-6144)*256 + tid);
  else if (bid < 7232)   tr(W1,   W1t, 1024, 256, (bid-6208)*256 + tid);
  else if (bid < 7296)   tr(W2,   W2t,  256,  64, (bid-7232)*256 + tid);
  else if (bid < 7552)   tr(Wv,   WvT,  256,  64, (bid-7296)*256 + tid);
  else {
    // Mct[(e*256+h)][hp] = 0.125 * sum_d Wsel[e,hp,d]*Wk[e,h,d]
    int idx = (bid - 7552) * 256 + tid;
    int hp = idx & 255, eh = idx >> 8;
    int e = eh >> 8, h = eh & 255;
    const float* ws = Wsel + ((long)e * 256 + hp) * 64;
    const float* wk = Wk   + ((long)e * 256 + h ) * 64;
    float s = 0.f;
    #pragma unroll 8
    for (int d = 0; d < 64; d++) s += ws[d] * wk[d];
    Mct[idx] = f2bfu(0.125f * s);
  }
}

// =====================================================================
// Wide GEMM: tile 64(M) x 256(N), BK=64, 512 threads = 8 waves (2x4 grid).
// ROUND-10 structure (verbatim revert; r12's BN=128 variant NaN'd and the
// defect was not identifiable by inspection -> do not ship it).
// =====================================================================
template<bool AF32, bool LRELU, bool OUTF32>
__global__ __launch_bounds__(512, 2) void k_gemm2(
    const void* __restrict__ Ap, int lda, long strideA,
    const unsigned short* __restrict__ Bt, long strideB,
    const float* __restrict__ bias, long strideBias,
    void* __restrict__ Cp, int ldc, long strideC,
    int K)
{
  __shared__ __align__(16) unsigned short Alds[2][64 * 64];    // 2 x 8 KB
  __shared__ __align__(16) unsigned short Blds[2][256 * 64];   // 2 x 32 KB

  const int tid = threadIdx.x;
  const int lane = tid & 63, w = tid >> 6;
  const int wr = w >> 2, wc = w & 3;
  const int lr = lane & 15, lg = lane >> 4;
  const int bm = blockIdx.x, bn = blockIdx.y, bz = blockIdx.z;

  f32x4_t acc[2][4];
  #pragma unroll
  for (int i = 0; i < 2; i++)
    #pragma unroll
    for (int j = 0; j < 4; j++) acc[i][j] = (f32x4_t){0.f, 0.f, 0.f, 0.f};

  const unsigned short* Bb = Bt + bz * strideB + (long)(bn * 256) * K;
  const float* Af32 = AF32 ? (const float*)Ap + bz * strideA + (long)(bm * 64) * lda : nullptr;
  const unsigned short* Abf = AF32 ? nullptr
      : (const unsigned short*)Ap + bz * strideA + (long)(bm * 64) * lda;
  const int nt = K >> 6;

  float4 ar0, ar1;   // in-flight A f32 registers (one K-step ahead)

  auto stageB = [&](int buf, int k0){
    #pragma unroll
    for (int i = 0; i < 4; i++) {
      int c = i * 512 + tid;
      int n = c >> 3, sl = c & 7;
      gll16(Bb + (long)n * K + k0 + (((sl ^ (n & 7)) & 7) << 3), &Blds[buf][c * 8]);
    }
  };
  auto issueA = [&](int buf, int k0){
    if (AF32) {
      int r0 = tid >> 4, q0 = tid & 15;
      ar0 = *reinterpret_cast<const float4*>(Af32 + (long)r0 * lda + k0 + q0 * 4);
      int c1 = tid + 512, r1 = c1 >> 4, q1 = c1 & 15;
      ar1 = *reinterpret_cast<const float4*>(Af32 + (long)r1 * lda + k0 + q1 * 4);
    } else {
      int row = tid >> 3, sl = tid & 7;
      gll16(Abf + (long)row * lda + k0 + (((sl ^ (row & 7)) & 7) << 3),
            &Alds[buf][tid * 8]);
    }
  };
  auto writeA = [&](int buf){
    if (AF32) {
      {
        int c = tid, row = c >> 4, q = c & 15;
        ushort4 u;
        u.x = f2bfu(ar0.x); u.y = f2bfu(ar0.y); u.z = f2bfu(ar0.z); u.w = f2bfu(ar0.w);
        int di = row * 64 + ((((q >> 1) ^ (row & 7)) & 7) << 3) + ((q & 1) << 2);
        *reinterpret_cast<ushort4*>(&Alds[buf][di]) = u;
      }
      {
        int c = tid + 512, row = c >> 4, q = c & 15;
        ushort4 u;
        u.x = f2bfu(ar1.x); u.y = f2bfu(ar1.y); u.z = f2bfu(ar1.z); u.w = f2bfu(ar1.w);
        int di = row * 64 + ((((q >> 1) ^ (row & 7)) & 7) << 3) + ((q & 1) << 2);
        *reinterpret_cast<ushort4*>(&Alds[buf][di]) = u;
      }
    }
  };

  // prologue: A first (oldest in vmcnt FIFO), then B; cvt waits on A only
  issueA(0, 0);
  stageB(0, 0);
  writeA(0);

  for (int t = 0; t < nt; t++) {
    const int cur = t & 1;
    asm volatile("s_waitcnt vmcnt(0) lgkmcnt(0)" ::: "memory");
    __builtin_amdgcn_s_barrier();
    __builtin_amdgcn_sched_barrier(0);
    if (t + 1 < nt) { issueA(cur ^ 1, (t + 1) * 64); stageB(cur ^ 1, (t + 1) * 64); }
    __builtin_amdgcn_sched_barrier(0);

    bf16x8_t af[2][2], bf[4][2];
    #pragma unroll
    for (int mf = 0; mf < 2; mf++)
      #pragma unroll
      for (int kk = 0; kk < 2; kk++) {
        int row = wr * 32 + mf * 16 + lr;
        af[mf][kk] = *reinterpret_cast<const bf16x8_t*>(
            &Alds[cur][row * 64 + ((((kk * 4 + lg) ^ (row & 7)) & 7) << 3)]);
      }
    #pragma unroll
    for (int nf = 0; nf < 4; nf++)
      #pragma unroll
      for (int kk = 0; kk < 2; kk++) {
        int n = wc * 64 + nf * 16 + lr;
        bf[nf][kk] = *reinterpret_cast<const bf16x8_t*>(
            &Blds[cur][n * 64 + ((((kk * 4 + lg) ^ (n & 7)) & 7) << 3)]);
      }
    #pragma unroll
    for (int kk = 0; kk < 2; kk++)
      #pragma unroll
      for (int mf = 0; mf < 2; mf++)
        #pragma unroll
        for (int nf = 0; nf < 4; nf++)
          acc[mf][nf] = __builtin_amdgcn_mfma_f32_16x16x32_bf16(af[mf][kk], bf[nf][kk], acc[mf][nf], 0, 0, 0);

    __builtin_amdgcn_sched_barrier(0);
    if (t + 1 < nt) writeA(cur ^ 1);   // f32: waits only on A's loads; B stays in flight
  }

  // epilogue: C/D layout col=lane&15, row=(lane>>4)*4+reg
  const float* bp = bias ? bias + bz * strideBias : nullptr;
  #pragma unroll
  for (int nf = 0; nf < 4; nf++) {
    int col = bn * 256 + wc * 64 + nf * 16 + lr;
    float bvv = bp ? bp[col] : 0.f;
    #pragma unroll
    for (int mf = 0; mf < 2; mf++) {
      #pragma unroll
      for (int r = 0; r < 4; r++) {
        int row = bm * 64 + wr * 32 + mf * 16 + lg * 4 + r;
        float v = acc[mf][nf][r] + bvv;
        if (LRELU) v = v > 0.f ? v : 0.01f * v;
        if (OUTF32)
          ((float*)Cp)[bz * strideC + (long)row * ldc + col] = v;
        else
          ((unsigned short*)Cp)[bz * strideC + (long)row * ldc + col] = f2bfu(v);
      }
    }
  }
}

// =====================================================================
// Attention split, ROUND-10 geometry (16-row blocks, 1024 blocks, 4/CU).
// =====================================================================
__global__ __launch_bounds__(512) void k_attnw(
    const unsigned short* __restrict__ others,  // [B][31][256] bf16
    const unsigned short* __restrict__ qbuf,    // [B][1024] bf16 (e*256+h)
    float* __restrict__ wbuf,                   // [B][4][31] unnormalized p
    float* __restrict__ wsum)                   // [B][4] sum of p
{
  __shared__ __align__(16) unsigned short olds[2][16 * 256];  // 2 x 8 KB

  const int tid = threadIdx.x;
  const int bm = blockIdx.x;
  const int row = tid >> 5, sub = tid & 31;    // 32 threads per row
  const int e = sub >> 3, ch = sub & 7;        // 4 heads x 8 chunks of 32h
  const long grow = (long)bm * 16 + row;

  bf16x8_t qr[4];
  #pragma unroll
  for (int j = 0; j < 4; j++)
    qr[j] = *reinterpret_cast<const bf16x8_t*>(
        &qbuf[grow * 1024 + e * 256 + ch * 32 + j * 8]);

  float psum = 0.f;

  auto stage = [&](int buf, int n){
    int r = tid >> 5, slot = tid & 31;         // 16 rows x 32 slots of 16B
    gll16(others + ((long)(bm * 16 + r) * NO_ + n) * 256 + ((slot ^ ((r & 7) << 2)) << 3),
          &olds[buf][tid * 8]);
  };

  stage(0, 0);

  for (int n = 0; n < NO_; n++) {
    const int cur = n & 1;
    __syncthreads();
    if (n + 1 < NO_) stage(cur ^ 1, n + 1);

    float d = 0.f;
    #pragma unroll
    for (int j = 0; j < 4; j++) {
      int slot = (ch * 4 + j) ^ ((row & 7) << 2);
      bf16x8_t o8 = *reinterpret_cast<const bf16x8_t*>(&olds[cur][row * 256 + slot * 8]);
      d = dot8(o8, qr[j], d);
    }
    d += __shfl_xor(d, 1);
    d += __shfl_xor(d, 2);
    d += __shfl_xor(d, 4);
    float p = __expf(d);
    psum += p;
    if (ch == 0) wbuf[grow * 124 + e * 31 + n] = p;
  }
  if (ch == 0) wsum[grow * 4 + e] = psum;
}

__global__ __launch_bounds__(512) void k_pv(
    const unsigned short* __restrict__ others,  // [B][31][256] bf16
    const unsigned short* __restrict__ WvT,     // [256][256] bf16 (col=e*64+d, k=h)
    const float* __restrict__ wbuf,             // [B][4][31]
    const float* __restrict__ wsum,             // [B][4]
    const float* __restrict__ bv,               // [256]
    unsigned short* __restrict__ critic)        // [B][1024]
{
  __shared__ __align__(16) unsigned short olds[2][16 * 256];  // 2 x 8 KB
  __shared__ float pl[2][64];                                 // [dbuf][16 rows][4 e]

  const int tid = threadIdx.x;
  const int lane = tid & 63, w = tid >> 6;
  const int lr = lane & 15, lg = lane >> 4;
  const int bm = blockIdx.x;
  const int e = w >> 1;                         // wave's 32 cols lie in head e

  // Wv fragments: wave w owns cols [w*32, w*32+32)  -> 64 VGPR
  bf16x8_t wv[2][8];
  #pragma unroll
  for (int nf = 0; nf < 2; nf++)
    #pragma unroll
    for (int kk = 0; kk < 8; kk++)
      wv[nf][kk] = *reinterpret_cast<const bf16x8_t*>(
          &WvT[(long)(w * 32 + nf * 16 + lr) * 256 + kk * 32 + lg * 8]);
  float bvv[2] = { bv[w * 32 + lr], bv[w * 32 + 16 + lr] };

  f32x4_t outa[2];
  outa[0] = (f32x4_t){0.f, 0.f, 0.f, 0.f};
  outa[1] = (f32x4_t){0.f, 0.f, 0.f, 0.f};

  auto stage = [&](int buf, int n){
    int r = tid >> 5, slot = tid & 31;
    gll16(others + ((long)(bm * 16 + r) * NO_ + n) * 256 + ((slot ^ ((r & 7) << 2)) << 3),
          &olds[buf][tid * 8]);
  };
  auto stagep = [&](int buf, int n){
    if (tid < 64)
      pl[buf][tid] = wbuf[((long)bm * 16 + (tid >> 2)) * 124 + (tid & 3) * 31 + n];
  };

  stage(0, 0); stagep(0, 0);

  for (int n = 0; n < NO_; n++) {
    const int cur = n & 1;
    __syncthreads();
    if (n + 1 < NO_) { stage(cur ^ 1, n + 1); stagep(cur ^ 1, n + 1); }

    f32x4_t va[2];
    va[0] = (f32x4_t){0.f, 0.f, 0.f, 0.f};
    va[1] = (f32x4_t){0.f, 0.f, 0.f, 0.f};
    #pragma unroll
    for (int kk = 0; kk < 8; kk++) {
      bf16x8_t af = *reinterpret_cast<const bf16x8_t*>(
          &olds[cur][lr * 256 + (((kk * 4 + lg) ^ ((lr & 7) << 2)) << 3)]);
      va[0] = __builtin_amdgcn_mfma_f32_16x16x32_bf16(af, wv[0][kk], va[0], 0, 0, 0);
      va[1] = __builtin_amdgcn_mfma_f32_16x16x32_bf16(af, wv[1][kk], va[1], 0, 0, 0);
    }

    #pragma unroll
    for (int r = 0; r < 4; r++) {
      float p = pl[cur][(lg * 4 + r) * 4 + e];
      #pragma unroll
      for (int nf = 0; nf < 2; nf++) {
        float v = va[nf][r] + bvv[nf];
        v = v > 0.f ? v : 0.01f * v;
        outa[nf][r] += p * v;
      }
    }
  }

  #pragma unroll
  for (int r = 0; r < 4; r++) {
    long grow = (long)bm * 16 + lg * 4 + r;
    float inv = 1.f / wsum[grow * 4 + e];
    #pragma unroll
    for (int nf = 0; nf < 2; nf++)
      critic[grow * 1024 + 768 + w * 32 + nf * 16 + lr] = f2bfu(outa[nf][r] * inv);
  }
}

// ---------------- small legacy GEMM (G6 only: N=64 tile) ---------------
template<bool AF32, bool LRELU, bool OUTF32>
__global__ __launch_bounds__(256) void k_gemm(
    const void* __restrict__ Ap, int lda, long strideA,
    const unsigned short* __restrict__ Bt, long strideB,
    const float* __restrict__ bias, long strideBias,
    void* __restrict__ Cp, int ldc, long strideC,
    int K)
{
  __shared__ __align__(16) unsigned short Alds[128][40];
  __shared__ __align__(16) unsigned short Blds[64][40];

  const int tid = threadIdx.x;
  const int bm = blockIdx.x, bn = blockIdx.y, bz = blockIdx.z;
  const int w = tid >> 6, lane = tid & 63;
  const int wr = (w >> 1) * 64, wc = (w & 1) * 32;
  const int lr = lane & 15, lk = (lane >> 4) * 8;

  f32x4_t acc[4][2];
  #pragma unroll
  for (int i = 0; i < 4; i++)
    #pragma unroll
    for (int j = 0; j < 2; j++) acc[i][j] = (f32x4_t){0.f, 0.f, 0.f, 0.f};

  const unsigned short* Bb = Bt + bz * strideB + (long)(bn * 64) * K;

  for (int k0 = 0; k0 < K; k0 += 32) {
    if (AF32) {
      const float* A = (const float*)Ap + bz * strideA + (long)(bm * 128) * lda + k0;
      #pragma unroll
      for (int i = 0; i < 4; i++) {
        int chunk = tid + i * 256;
        int m = chunk >> 3, kc = (chunk & 7) * 4;
        const float4 v = *reinterpret_cast<const float4*>(A + (long)m * lda + kc);
        ushort4 p;
        p.x = f2bfu(v.x); p.y = f2bfu(v.y); p.z = f2bfu(v.z); p.w = f2bfu(v.w);
        *reinterpret_cast<ushort4*>(&Alds[m][kc]) = p;
      }
    } else {
      const unsigned short* A = (const unsigned short*)Ap + bz * strideA + (long)(bm * 128) * lda + k0;
      #pragma unroll
      for (int i = 0; i < 4; i++) {
        int chunk = tid + i * 256;
        int m = chunk >> 3, kc = (chunk & 7) * 4;
        *reinterpret_cast<ushort4*>(&Alds[m][kc]) =
            *reinterpret_cast<const ushort4*>(A + (long)m * lda + kc);
      }
    }
    #pragma unroll
    for (int i = 0; i < 2; i++) {
      int chunk = tid + i * 256;
      int n = chunk >> 3, kc = (chunk & 7) * 4;
      *reinterpret_cast<ushort4*>(&Blds[n][kc]) =
          *reinterpret_cast<const ushort4*>(Bb + (long)n * K + k0 + kc);
    }
    __syncthreads();

    bf16x8_t bfr0 = *reinterpret_cast<const bf16x8_t*>(&Blds[wc + lr][lk]);
    bf16x8_t bfr1 = *reinterpret_cast<const bf16x8_t*>(&Blds[wc + 16 + lr][lk]);
    #pragma unroll
    for (int mf = 0; mf < 4; mf++) {
      bf16x8_t afr = *reinterpret_cast<const bf16x8_t*>(&Alds[wr + mf * 16 + lr][lk]);
      acc[mf][0] = __builtin_amdgcn_mfma_f32_16x16x32_bf16(afr, bfr0, acc[mf][0], 0, 0, 0);
      acc[mf][1] = __builtin_amdgcn_mfma_f32_16x16x32_bf16(afr, bfr1, acc[mf][1], 0, 0, 0);
    }
    __syncthreads();
  }

  const float* bp = bias ? bias + bz * strideBias : nullptr;
  #pragma unroll
  for (int nf = 0; nf < 2; nf++) {
    int col = bn * 64 + wc + nf * 16 + lr;
    float bvv = bp ? bp[col] : 0.f;
    #pragma unroll
    for (int mf = 0; mf < 4; mf++) {
      #pragma unroll
      for (int r = 0; r < 4; r++) {
        int row = bm * 128 + wr + mf * 16 + (lane >> 4) * 4 + r;
        float v = acc[mf][nf][r] + bvv;
        if (LRELU) v = v > 0.f ? v : 0.01f * v;
        if (OUTF32)
          ((float*)Cp)[bz * strideC + (long)row * ldc + col] = v;
        else
          ((unsigned short*)Cp)[bz * strideC + (long)row * ldc + col] = f2bfu(v);
      }
    }
  }
}

extern "C" void kernel_launch(void* const* d_in, const int* in_sizes, int n_in,
                              void* d_out, int out_size, void* d_ws, size_t ws_size,
                              hipStream_t stream)
{
  (void)in_sizes; (void)n_in; (void)out_size; (void)ws_size;
  const float* agent = (const float*)d_in[0];
  const float* state = (const float*)d_in[1];
  const float* mf    = (const float*)d_in[2];
  const float* mf2   = (const float*)d_in[3];
  const float* encW  = (const float*)d_in[4];
  const float* encb  = (const float*)d_in[5];
  const float* sW    = (const float*)d_in[6];
  const float* sb    = (const float*)d_in[7];
  const float* mfW   = (const float*)d_in[8];
  const float* mfb   = (const float*)d_in[9];
  const float* mf2W  = (const float*)d_in[10];
  const float* mf2b  = (const float*)d_in[11];
  const float* Wk    = (const float*)d_in[12];
  const float* Wsel  = (const float*)d_in[13];
  const float* Wv    = (const float*)d_in[14];
  const float* bv    = (const float*)d_in[15];
  const float* W1    = (const float*)d_in[16];
  const float* b1    = (const float*)d_in[17];
  const float* W2    = (const float*)d_in[18];
  const float* b2    = (const float*)d_in[19];
  float* out = (float*)d_out;

  char* ws = (char*)d_ws;
  size_t off = 0;
  auto alloc = [&](size_t bytes) -> char* {
    char* p = ws + off; off += (bytes + 255) & ~(size_t)255; return p;
  };
  unsigned short* others = (unsigned short*)alloc((size_t)B_SZ * NO_ * H_ * 2);   // [b][31][256]
  unsigned short* qbuf   = (unsigned short*)alloc((size_t)B_SZ * 1024 * 2);
  unsigned short* critic = (unsigned short*)alloc((size_t)B_SZ * 1024 * 2);
  unsigned short* h1buf  = (unsigned short*)alloc((size_t)B_SZ * H_ * 2);
  float*          wbuf   = (float*)alloc((size_t)B_SZ * HEADS_ * NO_ * 4);        // [b][4][31]
  float*          wsum   = (float*)alloc((size_t)B_SZ * HEADS_ * 4);              // [b][4]
  unsigned short* encWt  = (unsigned short*)alloc((size_t)NO_ * H_ * IDIM_ * 2);
  unsigned short* Mct    = (unsigned short*)alloc((size_t)1024 * 256 * 2);
  unsigned short* WvT    = (unsigned short*)alloc((size_t)256 * 256 * 2);
  unsigned short* sWt    = (unsigned short*)alloc((size_t)256 * 128 * 2);
  unsigned short* mfWt   = (unsigned short*)alloc((size_t)256 * 64 * 2);
  unsigned short* mf2Wt  = (unsigned short*)alloc((size_t)256 * 64 * 2);
  unsigned short* W1t    = (unsigned short*)alloc((size_t)256 * 1024 * 2);
  unsigned short* W2t    = (unsigned short*)alloc((size_t)64 * 256 * 2);

  // ---- prep: all weight transposes + Mct in ONE launch ----
  k_prep<<<dim3(8576), 256, 0, stream>>>(
      encW, sW, mfW, mf2W, W1, W2, Wv, Wsel, Wk,
      encWt, sWt, mfWt, mf2Wt, W1t, W2t, WvT, Mct);

  // ---- G1: others[b][n][:] = lrelu(agent[n+1] @ encW[n+1] + encb[n+1]) ----
  // MEASUREMENT ROUND: G1 launched TWICE (second launch writes identical
  // data — deterministic kernel, same inputs). bench_delta vs r10's 448us
  // = G1's true steady-state duration (rocprof top-5 is masked by harness
  // fills, so this is the only headless way to cost G1).
  k_gemm2<true, true, false><<<dim3(256, 1, NO_), 512, 0, stream>>>(
      agent + (size_t)B_SZ * IDIM_, IDIM_, (long)B_SZ * IDIM_,
      encWt, (long)H_ * IDIM_,
      encb + H_, H_,
      others, NO_ * H_, H_, IDIM_);
  k_gemm2<true, true, false><<<dim3(256, 1, NO_), 512, 0, stream>>>(
      agent + (size_t)B_SZ * IDIM_, IDIM_, (long)B_SZ * IDIM_,
      encWt, (long)H_ * IDIM_,
      encb + H_, H_,
      others, NO_ * H_, H_, IDIM_);

  // ---- G2: s_enc / mf_enc / mf2_enc into critic cols 0..767 ----
  k_gemm2<true, true, false><<<dim3(256, 1, 1), 512, 0, stream>>>(
      state, SD_, 0, sWt, 0, sb, 0, critic, 1024, 0, SD_);
  k_gemm2<true, true, false><<<dim3(256, 1, 1), 512, 0, stream>>>(
      mf, AD_, 0, mfWt, 0, mfb, 0, critic + 256, 1024, 0, AD_);
  k_gemm2<true, true, false><<<dim3(256, 1, 1), 512, 0, stream>>>(
      mf2, AD_, 0, mf2Wt, 0, mf2b, 0, critic + 512, 1024, 0, AD_);

  // ---- G3: q = s_enc @ Mct (scale folded), N=1024 ----
  k_gemm2<false, false, false><<<dim3(256, 4, 1), 512, 0, stream>>>(
      critic, 1024, 0, Mct, 0, nullptr, 0, qbuf, 1024, 0, 256);

  // ---- attention: logits + softmax weights (unnormalized p + psum) ----
  k_attnw<<<dim3(B_SZ / 16), 512, 0, stream>>>(others, qbuf, wbuf, wsum);

  // ---- weighted V-projection -> critic cols 768..1023 ----
  k_pv<<<dim3(B_SZ / 16), 512, 0, stream>>>(others, WvT, wbuf, wsum, bv, critic);

  // ---- G5: h1 = lrelu(critic @ W1 + b1) ----
  k_gemm2<false, true, false><<<dim3(256, 1, 1), 512, 0, stream>>>(
      critic, 1024, 0, W1t, 0, b1, 0, h1buf, H_, 0, 1024);

  // ---- G6: out = h1 @ W2 + b2 (f32) ----
  k_gemm<false, false, true><<<dim3(128, 1, 1), 256, 0, stream>>>(
      h1buf, H_, 0, W2t, 0, b2, 0, out, 64, 0, 256);
}

// Round 14
// 441.604 us; speedup vs baseline: 1.4301x; 1.4301x over previous
//
#include <hip/hip_runtime.h>
#include <hip/hip_bf16.h>

// Problem constants
#define N_AG   32
#define B_SZ   16384
#define SD_    128
#define AD_    64
#define IDIM_  192
#define H_     256
#define HEADS_ 4
#define AT_    64
#define NO_    31   // N_AG-1 "others"

typedef __attribute__((ext_vector_type(8))) short bf16x8_t;
typedef __attribute__((ext_vector_type(4))) float f32x4_t;
typedef __attribute__((ext_vector_type(4))) unsigned int u32x4_t;

__device__ inline unsigned short f2bfu(float f){
  union { __hip_bfloat16 h; unsigned short u; } cv;
  cv.h = __float2bfloat16(f);
  return cv.u;
}
__device__ inline float bflo(unsigned int u){
  union { float f; unsigned int i; } c; c.i = u << 16; return c.f;
}
__device__ inline float bfhi(unsigned int u){
  union { float f; unsigned int i; } c; c.i = u & 0xffff0000u; return c.f;
}

// async global->LDS 16B (dest = wave-uniform base + lane*16)
__device__ inline void gll16(const unsigned short* g, unsigned short* l) {
  __builtin_amdgcn_global_load_lds(
      (const __attribute__((address_space(1))) unsigned int*)g,
      (__attribute__((address_space(3))) unsigned int*)l, 16, 0, 0);
}

// 8-wide bf16 dot with f32 accumulate
__device__ inline float dot8(bf16x8_t a, bf16x8_t b, float acc){
  u32x4_t au = __builtin_bit_cast(u32x4_t, a);
  u32x4_t bu = __builtin_bit_cast(u32x4_t, b);
  #pragma unroll
  for (int i = 0; i < 4; i++) {
    acc = fmaf(bflo(au[i]), bflo(bu[i]), acc);
    acc = fmaf(bfhi(au[i]), bfhi(bu[i]), acc);
  }
  return acc;
}

// ==================== consolidated prep (transposes + Mct) ====================
__global__ __launch_bounds__(256) void k_prep(
    const float* __restrict__ encW, const float* __restrict__ sW,
    const float* __restrict__ mfW,  const float* __restrict__ mf2W,
    const float* __restrict__ W1,   const float* __restrict__ W2,
    const float* __restrict__ Wv,   const float* __restrict__ Wsel,
    const float* __restrict__ Wk,
    unsigned short* __restrict__ encWt, unsigned short* __restrict__ sWt,
    unsigned short* __restrict__ mfWt,  unsigned short* __restrict__ mf2Wt,
    unsigned short* __restrict__ W1t,   unsigned short* __restrict__ W2t,
    unsigned short* __restrict__ WvT,   unsigned short* __restrict__ Mct)
{
  const int bid = blockIdx.x, tid = threadIdx.x;
  auto tr = [&](const float* src, unsigned short* dst, int K, int N, int idx){
    int kn = K * N;
    int b = idx / kn, i = idx - b * kn;
    int n = i / K, k = i - n * K;
    dst[(long)b * kn + i] = f2bfu(src[(long)b * kn + (long)k * N + n]);
  };
  if (bid < 5952)        tr(encW + 192*256, encWt, 192, 256, bid*256 + tid);
  else if (bid < 6080)   tr(sW,   sWt,  128, 256, (bid-5952)*256 + tid);
  else if (bid < 6144)   tr(mfW,  mfWt,  64, 256, (bid-6080)*256 + tid);
  else if (bid < 6208)   tr(mf2W, mf2Wt, 64, 256, (bid-6144)*256 + tid);
  else if (bid < 7232)   tr(W1,   W1t, 1024, 256, (bid-6208)*256 + tid);
  else if (bid < 7296)   tr(W2,   W2t,  256,  64, (bid-7232)*256 + tid);
  else if (bid < 7552)   tr(Wv,   WvT,  256,  64, (bid-7296)*256 + tid);
  else {
    // Mct[(e*256+h)][hp] = 0.125 * sum_d Wsel[e,hp,d]*Wk[e,h,d]
    int idx = (bid - 7552) * 256 + tid;
    int hp = idx & 255, eh = idx >> 8;
    int e = eh >> 8, h = eh & 255;
    const float* ws = Wsel + ((long)e * 256 + hp) * 64;
    const float* wk = Wk   + ((long)e * 256 + h ) * 64;
    float s = 0.f;
    #pragma unroll 8
    for (int d = 0; d < 64; d++) s += ws[d] * wk[d];
    Mct[idx] = f2bfu(0.125f * s);
  }
}

// =====================================================================
// Wide GEMM: tile 64(M) x 256(N), BK=64, 512 threads = 8 waves (2x4 grid).
// ROUND-14: counted-vmcnt depth-2 schedule on the PROVEN r10 index math.
// r13 measured G1 = 183us vs 104us HBM floor (57% duty): r10's per-step
// vmcnt(0) drain idles each wave every K-step. New schedule: loop-top
// waits vmcnt(6) [f32-A; 5 bf16-A] = "tile t resident, tile t+1 in
// flight"; stage t+2 issued after a WAR barrier post-compute. Waves keep
// >=6 VMEM ops outstanding across barriers. Count-robustness: 6-newest
// ops are exactly group(t+2) (gll16 mutual order preserved; sched_barrier
// pins groups; older/newer extra loads only make the wait conservative).
// WAR: stage(t+2) writes buf cur; its readers retired before the post-
// compute barrier (ds_reads drained before MFMA use).
// =====================================================================
template<bool AF32, bool LRELU, bool OUTF32>
__global__ __launch_bounds__(512, 2) void k_gemm2(
    const void* __restrict__ Ap, int lda, long strideA,
    const unsigned short* __restrict__ Bt, long strideB,
    const float* __restrict__ bias, long strideBias,
    void* __restrict__ Cp, int ldc, long strideC,
    int K)
{
  __shared__ __align__(16) unsigned short Alds[2][64 * 64];    // 2 x 8 KB
  __shared__ __align__(16) unsigned short Blds[2][256 * 64];   // 2 x 32 KB

  const int tid = threadIdx.x;
  const int lane = tid & 63, w = tid >> 6;
  const int wr = w >> 2, wc = w & 3;
  const int lr = lane & 15, lg = lane >> 4;
  const int bm = blockIdx.x, bn = blockIdx.y, bz = blockIdx.z;

  f32x4_t acc[2][4];
  #pragma unroll
  for (int i = 0; i < 2; i++)
    #pragma unroll
    for (int j = 0; j < 4; j++) acc[i][j] = (f32x4_t){0.f, 0.f, 0.f, 0.f};

  const unsigned short* Bb = Bt + bz * strideB + (long)(bn * 256) * K;
  const float* Af32 = AF32 ? (const float*)Ap + bz * strideA + (long)(bm * 64) * lda : nullptr;
  const unsigned short* Abf = AF32 ? nullptr
      : (const unsigned short*)Ap + bz * strideA + (long)(bm * 64) * lda;
  const int nt = K >> 6;

  float4 ar0, ar1;   // in-flight A f32 registers (one K-step ahead)

  auto stageB = [&](int buf, int k0){
    #pragma unroll
    for (int i = 0; i < 4; i++) {
      int c = i * 512 + tid;
      int n = c >> 3, sl = c & 7;
      gll16(Bb + (long)n * K + k0 + (((sl ^ (n & 7)) & 7) << 3), &Blds[buf][c * 8]);
    }
  };
  auto issueA = [&](int buf, int k0){
    if (AF32) {
      int r0 = tid >> 4, q0 = tid & 15;
      ar0 = *reinterpret_cast<const float4*>(Af32 + (long)r0 * lda + k0 + q0 * 4);
      int c1 = tid + 512, r1 = c1 >> 4, q1 = c1 & 15;
      ar1 = *reinterpret_cast<const float4*>(Af32 + (long)r1 * lda + k0 + q1 * 4);
    } else {
      int row = tid >> 3, sl = tid & 7;
      gll16(Abf + (long)row * lda + k0 + (((sl ^ (row & 7)) & 7) << 3),
            &Alds[buf][tid * 8]);
    }
  };
  auto writeA = [&](int buf){
    if (AF32) {
      {
        int c = tid, row = c >> 4, q = c & 15;
        ushort4 u;
        u.x = f2bfu(ar0.x); u.y = f2bfu(ar0.y); u.z = f2bfu(ar0.z); u.w = f2bfu(ar0.w);
        int di = row * 64 + ((((q >> 1) ^ (row & 7)) & 7) << 3) + ((q & 1) << 2);
        *reinterpret_cast<ushort4*>(&Alds[buf][di]) = u;
      }
      {
        int c = tid + 512, row = c >> 4, q = c & 15;
        ushort4 u;
        u.x = f2bfu(ar1.x); u.y = f2bfu(ar1.y); u.z = f2bfu(ar1.z); u.w = f2bfu(ar1.w);
        int di = row * 64 + ((((q >> 1) ^ (row & 7)) & 7) << 3) + ((q & 1) << 2);
        *reinterpret_cast<ushort4*>(&Alds[buf][di]) = u;
      }
    }
  };

  // prologue: group0 (A0 oldest), writeA(0) (waits A0 regs only), then group1
  issueA(0, 0);
  stageB(0, 0);
  writeA(0);
  __builtin_amdgcn_sched_barrier(0);
  if (nt > 1) { issueA(1, 64); stageB(1, 64); }
  __builtin_amdgcn_sched_barrier(0);

  for (int t = 0; t < nt; t++) {
    const int cur = t & 1;
    if (t + 1 < nt) {
      if (AF32) asm volatile("s_waitcnt vmcnt(6) lgkmcnt(0)" ::: "memory");
      else      asm volatile("s_waitcnt vmcnt(5) lgkmcnt(0)" ::: "memory");
    } else {
      asm volatile("s_waitcnt vmcnt(0) lgkmcnt(0)" ::: "memory");
    }
    __builtin_amdgcn_s_barrier();
    __builtin_amdgcn_sched_barrier(0);

    bf16x8_t af[2][2], bf[4][2];
    #pragma unroll
    for (int mf = 0; mf < 2; mf++)
      #pragma unroll
      for (int kk = 0; kk < 2; kk++) {
        int row = wr * 32 + mf * 16 + lr;
        af[mf][kk] = *reinterpret_cast<const bf16x8_t*>(
            &Alds[cur][row * 64 + ((((kk * 4 + lg) ^ (row & 7)) & 7) << 3)]);
      }
    #pragma unroll
    for (int nf = 0; nf < 4; nf++)
      #pragma unroll
      for (int kk = 0; kk < 2; kk++) {
        int n = wc * 64 + nf * 16 + lr;
        bf[nf][kk] = *reinterpret_cast<const bf16x8_t*>(
            &Blds[cur][n * 64 + ((((kk * 4 + lg) ^ (n & 7)) & 7) << 3)]);
      }
    #pragma unroll
    for (int kk = 0; kk < 2; kk++)
      #pragma unroll
      for (int mf = 0; mf < 2; mf++)
        #pragma unroll
        for (int nf = 0; nf < 4; nf++)
          acc[mf][nf] = __builtin_amdgcn_mfma_f32_16x16x32_bf16(af[mf][kk], bf[nf][kk], acc[mf][nf], 0, 0, 0);

    __builtin_amdgcn_sched_barrier(0);
    if (t + 1 < nt) writeA(cur ^ 1);       // A(t+1) cvt+ds_write into Alds[cur^1]
    if (t + 2 < nt) {
      __builtin_amdgcn_s_barrier();        // WAR: all waves done reading buf cur
      __builtin_amdgcn_sched_barrier(0);
      issueA(cur, (t + 2) * 64);           // bf16: gll16 into Alds[cur]; f32: regs
      stageB(cur, (t + 2) * 64);
      __builtin_amdgcn_sched_barrier(0);
    }
  }

  // epilogue: C/D layout col=lane&15, row=(lane>>4)*4+reg
  const float* bp = bias ? bias + bz * strideBias : nullptr;
  #pragma unroll
  for (int nf = 0; nf < 4; nf++) {
    int col = bn * 256 + wc * 64 + nf * 16 + lr;
    float bvv = bp ? bp[col] : 0.f;
    #pragma unroll
    for (int mf = 0; mf < 2; mf++) {
      #pragma unroll
      for (int r = 0; r < 4; r++) {
        int row = bm * 64 + wr * 32 + mf * 16 + lg * 4 + r;
        float v = acc[mf][nf][r] + bvv;
        if (LRELU) v = v > 0.f ? v : 0.01f * v;
        if (OUTF32)
          ((float*)Cp)[bz * strideC + (long)row * ldc + col] = v;
        else
          ((unsigned short*)Cp)[bz * strideC + (long)row * ldc + col] = f2bfu(v);
      }
    }
  }
}

// =====================================================================
// Attention split, ROUND-10 geometry (16-row blocks, 1024 blocks, 4/CU).
// =====================================================================
__global__ __launch_bounds__(512) void k_attnw(
    const unsigned short* __restrict__ others,  // [B][31][256] bf16
    const unsigned short* __restrict__ qbuf,    // [B][1024] bf16 (e*256+h)
    float* __restrict__ wbuf,                   // [B][4][31] unnormalized p
    float* __restrict__ wsum)                   // [B][4] sum of p
{
  __shared__ __align__(16) unsigned short olds[2][16 * 256];  // 2 x 8 KB

  const int tid = threadIdx.x;
  const int bm = blockIdx.x;
  const int row = tid >> 5, sub = tid & 31;    // 32 threads per row
  const int e = sub >> 3, ch = sub & 7;        // 4 heads x 8 chunks of 32h
  const long grow = (long)bm * 16 + row;

  bf16x8_t qr[4];
  #pragma unroll
  for (int j = 0; j < 4; j++)
    qr[j] = *reinterpret_cast<const bf16x8_t*>(
        &qbuf[grow * 1024 + e * 256 + ch * 32 + j * 8]);

  float psum = 0.f;

  auto stage = [&](int buf, int n){
    int r = tid >> 5, slot = tid & 31;         // 16 rows x 32 slots of 16B
    gll16(others + ((long)(bm * 16 + r) * NO_ + n) * 256 + ((slot ^ ((r & 7) << 2)) << 3),
          &olds[buf][tid * 8]);
  };

  stage(0, 0);

  for (int n = 0; n < NO_; n++) {
    const int cur = n & 1;
    __syncthreads();
    if (n + 1 < NO_) stage(cur ^ 1, n + 1);

    float d = 0.f;
    #pragma unroll
    for (int j = 0; j < 4; j++) {
      int slot = (ch * 4 + j) ^ ((row & 7) << 2);
      bf16x8_t o8 = *reinterpret_cast<const bf16x8_t*>(&olds[cur][row * 256 + slot * 8]);
      d = dot8(o8, qr[j], d);
    }
    d += __shfl_xor(d, 1);
    d += __shfl_xor(d, 2);
    d += __shfl_xor(d, 4);
    float p = __expf(d);
    psum += p;
    if (ch == 0) wbuf[grow * 124 + e * 31 + n] = p;
  }
  if (ch == 0) wsum[grow * 4 + e] = psum;
}

__global__ __launch_bounds__(512) void k_pv(
    const unsigned short* __restrict__ others,  // [B][31][256] bf16
    const unsigned short* __restrict__ WvT,     // [256][256] bf16 (col=e*64+d, k=h)
    const float* __restrict__ wbuf,             // [B][4][31]
    const float* __restrict__ wsum,             // [B][4]
    const float* __restrict__ bv,               // [256]
    unsigned short* __restrict__ critic)        // [B][1024]
{
  __shared__ __align__(16) unsigned short olds[2][16 * 256];  // 2 x 8 KB
  __shared__ float pl[2][64];                                 // [dbuf][16 rows][4 e]

  const int tid = threadIdx.x;
  const int lane = tid & 63, w = tid >> 6;
  const int lr = lane & 15, lg = lane >> 4;
  const int bm = blockIdx.x;
  const int e = w >> 1;                         // wave's 32 cols lie in head e

  // Wv fragments: wave w owns cols [w*32, w*32+32)  -> 64 VGPR
  bf16x8_t wv[2][8];
  #pragma unroll
  for (int nf = 0; nf < 2; nf++)
    #pragma unroll
    for (int kk = 0; kk < 8; kk++)
      wv[nf][kk] = *reinterpret_cast<const bf16x8_t*>(
          &WvT[(long)(w * 32 + nf * 16 + lr) * 256 + kk * 32 + lg * 8]);
  float bvv[2] = { bv[w * 32 + lr], bv[w * 32 + 16 + lr] };

  f32x4_t outa[2];
  outa[0] = (f32x4_t){0.f, 0.f, 0.f, 0.f};
  outa[1] = (f32x4_t){0.f, 0.f, 0.f, 0.f};

  auto stage = [&](int buf, int n){
    int r = tid >> 5, slot = tid & 31;
    gll16(others + ((long)(bm * 16 + r) * NO_ + n) * 256 + ((slot ^ ((r & 7) << 2)) << 3),
          &olds[buf][tid * 8]);
  };
  auto stagep = [&](int buf, int n){
    if (tid < 64)
      pl[buf][tid] = wbuf[((long)bm * 16 + (tid >> 2)) * 124 + (tid & 3) * 31 + n];
  };

  stage(0, 0); stagep(0, 0);

  for (int n = 0; n < NO_; n++) {
    const int cur = n & 1;
    __syncthreads();
    if (n + 1 < NO_) { stage(cur ^ 1, n + 1); stagep(cur ^ 1, n + 1); }

    f32x4_t va[2];
    va[0] = (f32x4_t){0.f, 0.f, 0.f, 0.f};
    va[1] = (f32x4_t){0.f, 0.f, 0.f, 0.f};
    #pragma unroll
    for (int kk = 0; kk < 8; kk++) {
      bf16x8_t af = *reinterpret_cast<const bf16x8_t*>(
          &olds[cur][lr * 256 + (((kk * 4 + lg) ^ ((lr & 7) << 2)) << 3)]);
      va[0] = __builtin_amdgcn_mfma_f32_16x16x32_bf16(af, wv[0][kk], va[0], 0, 0, 0);
      va[1] = __builtin_amdgcn_mfma_f32_16x16x32_bf16(af, wv[1][kk], va[1], 0, 0, 0);
    }

    #pragma unroll
    for (int r = 0; r < 4; r++) {
      float p = pl[cur][(lg * 4 + r) * 4 + e];
      #pragma unroll
      for (int nf = 0; nf < 2; nf++) {
        float v = va[nf][r] + bvv[nf];
        v = v > 0.f ? v : 0.01f * v;
        outa[nf][r] += p * v;
      }
    }
  }

  #pragma unroll
  for (int r = 0; r < 4; r++) {
    long grow = (long)bm * 16 + lg * 4 + r;
    float inv = 1.f / wsum[grow * 4 + e];
    #pragma unroll
    for (int nf = 0; nf < 2; nf++)
      critic[grow * 1024 + 768 + w * 32 + nf * 16 + lr] = f2bfu(outa[nf][r] * inv);
  }
}

// ---------------- small legacy GEMM (G6 only: N=64 tile) ---------------
template<bool AF32, bool LRELU, bool OUTF32>
__global__ __launch_bounds__(256) void k_gemm(
    const void* __restrict__ Ap, int lda, long strideA,
    const unsigned short* __restrict__ Bt, long strideB,
    const float* __restrict__ bias, long strideBias,
    void* __restrict__ Cp, int ldc, long strideC,
    int K)
{
  __shared__ __align__(16) unsigned short Alds[128][40];
  __shared__ __align__(16) unsigned short Blds[64][40];

  const int tid = threadIdx.x;
  const int bm = blockIdx.x, bn = blockIdx.y, bz = blockIdx.z;
  const int w = tid >> 6, lane = tid & 63;
  const int wr = (w >> 1) * 64, wc = (w & 1) * 32;
  const int lr = lane & 15, lk = (lane >> 4) * 8;

  f32x4_t acc[4][2];
  #pragma unroll
  for (int i = 0; i < 4; i++)
    #pragma unroll
    for (int j = 0; j < 2; j++) acc[i][j] = (f32x4_t){0.f, 0.f, 0.f, 0.f};

  const unsigned short* Bb = Bt + bz * strideB + (long)(bn * 64) * K;

  for (int k0 = 0; k0 < K; k0 += 32) {
    if (AF32) {
      const float* A = (const float*)Ap + bz * strideA + (long)(bm * 128) * lda + k0;
      #pragma unroll
      for (int i = 0; i < 4; i++) {
        int chunk = tid + i * 256;
        int m = chunk >> 3, kc = (chunk & 7) * 4;
        const float4 v = *reinterpret_cast<const float4*>(A + (long)m * lda + kc);
        ushort4 p;
        p.x = f2bfu(v.x); p.y = f2bfu(v.y); p.z = f2bfu(v.z); p.w = f2bfu(v.w);
        *reinterpret_cast<ushort4*>(&Alds[m][kc]) = p;
      }
    } else {
      const unsigned short* A = (const unsigned short*)Ap + bz * strideA + (long)(bm * 128) * lda + k0;
      #pragma unroll
      for (int i = 0; i < 4; i++) {
        int chunk = tid + i * 256;
        int m = chunk >> 3, kc = (chunk & 7) * 4;
        *reinterpret_cast<ushort4*>(&Alds[m][kc]) =
            *reinterpret_cast<const ushort4*>(A + (long)m * lda + kc);
      }
    }
    #pragma unroll
    for (int i = 0; i < 2; i++) {
      int chunk = tid + i * 256;
      int n = chunk >> 3, kc = (chunk & 7) * 4;
      *reinterpret_cast<ushort4*>(&Blds[n][kc]) =
          *reinterpret_cast<const ushort4*>(Bb + (long)n * K + k0 + kc);
    }
    __syncthreads();

    bf16x8_t bfr0 = *reinterpret_cast<const bf16x8_t*>(&Blds[wc + lr][lk]);
    bf16x8_t bfr1 = *reinterpret_cast<const bf16x8_t*>(&Blds[wc + 16 + lr][lk]);
    #pragma unroll
    for (int mf = 0; mf < 4; mf++) {
      bf16x8_t afr = *reinterpret_cast<const bf16x8_t*>(&Alds[wr + mf * 16 + lr][lk]);
      acc[mf][0] = __builtin_amdgcn_mfma_f32_16x16x32_bf16(afr, bfr0, acc[mf][0], 0, 0, 0);
      acc[mf][1] = __builtin_amdgcn_mfma_f32_16x16x32_bf16(afr, bfr1, acc[mf][1], 0, 0, 0);
    }
    __syncthreads();
  }

  const float* bp = bias ? bias + bz * strideBias : nullptr;
  #pragma unroll
  for (int nf = 0; nf < 2; nf++) {
    int col = bn * 64 + wc + nf * 16 + lr;
    float bvv = bp ? bp[col] : 0.f;
    #pragma unroll
    for (int mf = 0; mf < 4; mf++) {
      #pragma unroll
      for (int r = 0; r < 4; r++) {
        int row = bm * 128 + wr + mf * 16 + (lane >> 4) * 4 + r;
        float v = acc[mf][nf][r] + bvv;
        if (LRELU) v = v > 0.f ? v : 0.01f * v;
        if (OUTF32)
          ((float*)Cp)[bz * strideC + (long)row * ldc + col] = v;
        else
          ((unsigned short*)Cp)[bz * strideC + (long)row * ldc + col] = f2bfu(v);
      }
    }
  }
}

extern "C" void kernel_launch(void* const* d_in, const int* in_sizes, int n_in,
                              void* d_out, int out_size, void* d_ws, size_t ws_size,
                              hipStream_t stream)
{
  (void)in_sizes; (void)n_in; (void)out_size; (void)ws_size;
  const float* agent = (const float*)d_in[0];
  const float* state = (const float*)d_in[1];
  const float* mf    = (const float*)d_in[2];
  const float* mf2   = (const float*)d_in[3];
  const float* encW  = (const float*)d_in[4];
  const float* encb  = (const float*)d_in[5];
  const float* sW    = (const float*)d_in[6];
  const float* sb    = (const float*)d_in[7];
  const float* mfW   = (const float*)d_in[8];
  const float* mfb   = (const float*)d_in[9];
  const float* mf2W  = (const float*)d_in[10];
  const float* mf2b  = (const float*)d_in[11];
  const float* Wk    = (const float*)d_in[12];
  const float* Wsel  = (const float*)d_in[13];
  const float* Wv    = (const float*)d_in[14];
  const float* bv    = (const float*)d_in[15];
  const float* W1    = (const float*)d_in[16];
  const float* b1    = (const float*)d_in[17];
  const float* W2    = (const float*)d_in[18];
  const float* b2    = (const float*)d_in[19];
  float* out = (float*)d_out;

  char* ws = (char*)d_ws;
  size_t off = 0;
  auto alloc = [&](size_t bytes) -> char* {
    char* p = ws + off; off += (bytes + 255) & ~(size_t)255; return p;
  };
  unsigned short* others = (unsigned short*)alloc((size_t)B_SZ * NO_ * H_ * 2);   // [b][31][256]
  unsigned short* qbuf   = (unsigned short*)alloc((size_t)B_SZ * 1024 * 2);
  unsigned short* critic = (unsigned short*)alloc((size_t)B_SZ * 1024 * 2);
  unsigned short* h1buf  = (unsigned short*)alloc((size_t)B_SZ * H_ * 2);
  float*          wbuf   = (float*)alloc((size_t)B_SZ * HEADS_ * NO_ * 4);        // [b][4][31]
  float*          wsum   = (float*)alloc((size_t)B_SZ * HEADS_ * 4);              // [b][4]
  unsigned short* encWt  = (unsigned short*)alloc((size_t)NO_ * H_ * IDIM_ * 2);
  unsigned short* Mct    = (unsigned short*)alloc((size_t)1024 * 256 * 2);
  unsigned short* WvT    = (unsigned short*)alloc((size_t)256 * 256 * 2);
  unsigned short* sWt    = (unsigned short*)alloc((size_t)256 * 128 * 2);
  unsigned short* mfWt   = (unsigned short*)alloc((size_t)256 * 64 * 2);
  unsigned short* mf2Wt  = (unsigned short*)alloc((size_t)256 * 64 * 2);
  unsigned short* W1t    = (unsigned short*)alloc((size_t)256 * 1024 * 2);
  unsigned short* W2t    = (unsigned short*)alloc((size_t)64 * 256 * 2);

  // ---- prep: all weight transposes + Mct in ONE launch ----
  k_prep<<<dim3(8576), 256, 0, stream>>>(
      encW, sW, mfW, mf2W, W1, W2, Wv, Wsel, Wk,
      encWt, sWt, mfWt, mf2Wt, W1t, W2t, WvT, Mct);

  // ---- G1: others[b][n][:] = lrelu(agent[n+1] @ encW[n+1] + encb[n+1]) ----
  k_gemm2<true, true, false><<<dim3(256, 1, NO_), 512, 0, stream>>>(
      agent + (size_t)B_SZ * IDIM_, IDIM_, (long)B_SZ * IDIM_,
      encWt, (long)H_ * IDIM_,
      encb + H_, H_,
      others, NO_ * H_, H_, IDIM_);

  // ---- G2: s_enc / mf_enc / mf2_enc into critic cols 0..767 ----
  k_gemm2<true, true, false><<<dim3(256, 1, 1), 512, 0, stream>>>(
      state, SD_, 0, sWt, 0, sb, 0, critic, 1024, 0, SD_);
  k_gemm2<true, true, false><<<dim3(256, 1, 1), 512, 0, stream>>>(
      mf, AD_, 0, mfWt, 0, mfb, 0, critic + 256, 1024, 0, AD_);
  k_gemm2<true, true, false><<<dim3(256, 1, 1), 512, 0, stream>>>(
      mf2, AD_, 0, mf2Wt, 0, mf2b, 0, critic + 512, 1024, 0, AD_);

  // ---- G3: q = s_enc @ Mct (scale folded), N=1024 ----
  k_gemm2<false, false, false><<<dim3(256, 4, 1), 512, 0, stream>>>(
      critic, 1024, 0, Mct, 0, nullptr, 0, qbuf, 1024, 0, 256);

  // ---- attention: logits + softmax weights (unnormalized p + psum) ----
  k_attnw<<<dim3(B_SZ / 16), 512, 0, stream>>>(others, qbuf, wbuf, wsum);

  // ---- weighted V-projection -> critic cols 768..1023 ----
  k_pv<<<dim3(B_SZ / 16), 512, 0, stream>>>(others, WvT, wbuf, wsum, bv, critic);

  // ---- G5: h1 = lrelu(critic @ W1 + b1) ----
  k_gemm2<false, true, false><<<dim3(256, 1, 1), 512, 0, stream>>>(
      critic, 1024, 0, W1t, 0, b1, 0, h1buf, H_, 0, 1024);

  // ---- G6: out = h1 @ W2 + b2 (f32) ----
  k_gemm<false, false, true><<<dim3(128, 1, 1), 256, 0, stream>>>(
      h1buf, H_, 0, W2t, 0, b2, 0, out, 64, 0, 256);
}